// Round 12
// baseline (315.635 us; speedup 1.0000x reference)
//
#include <hip/hip_runtime.h>
#include <hip/hip_fp16.h>

#define HH 512
#define WW 512
#define NB 4

// ---------------- Stage 1: 11x11 convs (1->8, pos & neg) + spike/WTA logic ----------------
// EXACT round-11 version (verified; stage1 proven insensitive — do not touch).
#define K1 11
#define PAD1 5
#define T1X 32
#define T1Y 16
#define IN1X 42
#define IN1Y 26
#define S1 44

__device__ __forceinline__ unsigned conv8_pass2(const float* __restrict__ sm,
                                                const float* __restrict__ Wb,
                                                int py, int px)
{
    float acc[8][2];
    #pragma unroll
    for (int c = 0; c < 8; c++) { acc[c][0] = 0.f; acc[c][1] = 0.f; }

    #pragma unroll 1
    for (int ky = 0; ky < K1; ky++) {
        const float2* rp = (const float2*)&sm[(py + ky) * S1 + px];
        float a[12];
        #pragma unroll
        for (int r = 0; r < 6; r++) *(float2*)&a[2 * r] = rp[r];
        #pragma unroll
        for (int c = 0; c < 8; c++) {
            #pragma unroll
            for (int kx = 0; kx < K1; kx++) {
                const float wv = Wb[c * 121 + ky * 11 + kx];
                acc[c][0] = fmaf(a[kx],     wv, acc[c][0]);
                acc[c][1] = fmaf(a[kx + 1], wv, acc[c][1]);
            }
        }
    }
    unsigned bits = 0;
    #pragma unroll
    for (int c = 0; c < 8; c++) {
        bits |= (acc[c][0] >= 1.f ? 1u : 0u) << (c * 2);
        bits |= (acc[c][1] >= 1.f ? 1u : 0u) << (c * 2 + 1);
    }
    return bits;
}

__global__ __launch_bounds__(256, 8) void stage1_kernel(
    const float* __restrict__ inp, const float* __restrict__ Wb,
    unsigned char* __restrict__ border)
{
    __shared__ __align__(16) float s0[IN1Y * S1];
    __shared__ __align__(16) float s1[IN1Y * S1];

    const int b   = blockIdx.z;
    const int tx0 = blockIdx.x * T1X;
    const int ty0 = blockIdx.y * T1Y;
    const float* in0 = inp + ((size_t)b * 2 + 0) * (HH * WW);
    const float* in1 = inp + ((size_t)b * 2 + 1) * (HH * WW);

    for (int i = threadIdx.x; i < IN1Y * IN1X; i += 256) {
        int iy = i / IN1X, ix = i - iy * IN1X;
        int gy = ty0 + iy - PAD1, gx = tx0 + ix - PAD1;
        bool ok = (gy >= 0) & (gy < HH) & (gx >= 0) & (gx < WW);
        int idx = gy * WW + gx;
        s0[iy * S1 + ix] = ok ? in0[idx] : 0.f;
        s1[iy * S1 + ix] = ok ? in1[idx] : 0.f;
    }
    __syncthreads();

    const int lx = threadIdx.x & 15;
    const int ly = threadIdx.x >> 4;
    const int px = lx * 2;
    const int py = ly;

    const unsigned bitP = conv8_pass2(s0, Wb, py, px);
    const unsigned bitN = conv8_pass2(s1, Wb, py, px);

    const int gy = ty0 + py;
    const int gxbase = tx0 + px;

    float vm[2];
    #pragma unroll
    for (int p = 0; p < 2; p++)
        vm[p] = s0[(py + PAD1) * S1 + px + PAD1 + p]
              + s1[(py + PAD1) * S1 + px + PAD1 + p];

    float b13[4][2], b24[4][2];
    #pragma unroll
    for (int o = 0; o < 4; o++) {
        #pragma unroll
        for (int p = 0; p < 2; p++) {
            float pe = (float)((bitP >> (4 * o + p))     & 1u);
            float po = (float)((bitP >> (4 * o + 2 + p)) & 1u);
            float ne = (float)((bitN >> (4 * o + p))     & 1u);
            float no = (float)((bitN >> (4 * o + 2 + p)) & 1u);
            float sa = (vm[p] * (pe - 1.5f * no) >= 1.f) ? 1.f : 0.f;
            float sb = (vm[p] * (ne - 1.5f * po) >= 1.f) ? 1.f : 0.f;
            b13[o][p] = sa + sb;
            float sc = (vm[p] * (po - 1.5f * ne) >= 1.f) ? 1.f : 0.f;
            float sd = (vm[p] * (no - 1.5f * pe) >= 1.f) ? 1.f : 0.f;
            b24[o][p] = sc + sd;
        }
    }
    float mxp[2];
    #pragma unroll
    for (int p = 0; p < 2; p++) {
        float m = 0.f;
        #pragma unroll
        for (int o = 0; o < 4; o++) m = fmaxf(m, fabsf(b13[o][p] - b24[o][p]));
        mxp[p] = m;
    }
    #pragma unroll
    for (int o = 0; o < 4; o++) {
        unsigned short w0 = 0, w1 = 0, w2 = 0, w3 = 0;
        #pragma unroll
        for (int p = 0; p < 2; p++) {
            float d   = b13[o][p] - b24[o][p];
            float wta = (fabsf(d) == mxp[p]) ? 1.f : 0.f;
            float b1p = (wta * d >= 1.f)    ? 1.f : 0.f;
            float b1n = (-(wta * d) >= 1.f) ? 1.f : 0.f;
            w0 |= (unsigned short)(unsigned char)(b1p * b13[o][p]) << (8 * p);
            w1 |= (unsigned short)(unsigned char)(b1p * b24[o][p]) << (8 * p);
            w2 |= (unsigned short)(unsigned char)(b1n * b24[o][p]) << (8 * p);
            w3 |= (unsigned short)(unsigned char)(b1n * b13[o][p]) << (8 * p);
        }
        size_t base = (((size_t)b * 16 + 4 * o) * HH + gy) * WW + gxbase;
        *(unsigned short*)&border[base]                       = w0;
        *(unsigned short*)&border[base + (size_t)HH * WW]     = w1;
        *(unsigned short*)&border[base + (size_t)2 * HH * WW] = w2;
        *(unsigned short*)&border[base + (size_t)3 * HH * WW] = w3;
    }
}

// ---------------- Stage 2: depthwise 23x23 conv, f16 LDS tile + fused pair combine -------
// One block per (batch, channel-PAIR); channels 2p,2p+1 staged+conv'd sequentially; writes
// term = spike(c_even) & ~spike(c_odd) as one u8 plane (combine then just sums 8 planes).
// Tile stored as f16 (0/1/2 exact): fmaf((float)h, w, acc) -> v_fma_mix_f32, no cvt tax.
#define K2 23
#define PAD2 11
#define T2X 32
#define T2Y 128
#define F16ROW 28      // row stride in dwords (=56 f16 cols, 112 B: rows 16B-aligned)
#define R2 150         // staged rows: ty0-11 .. ty0+138

__global__ __launch_bounds__(256, 4) void stage2_kernel(
    const unsigned char* __restrict__ border, const float* __restrict__ Wg,
    unsigned char* __restrict__ termp)
{
    __shared__ __align__(16) unsigned tile[R2 * F16ROW];   // f16 tile, 16.8 KB

    const int z   = blockIdx.z;
    const int b   = z >> 3;
    const int pr  = z & 7;            // pair index: channels 2pr, 2pr+1
    const int tx0 = blockIdx.x * T2X;
    const int ty0 = blockIdx.y * T2Y;

    const int lx = threadIdx.x & 3;    // 4 x-groups of 8 px
    const int ly = threadIdx.x >> 2;   // 64 y-groups of 2 rows
    const int px = lx * 8;
    const int py = ly * 2;

    unsigned sprev = 0, term = 0;

    #pragma unroll 1
    for (int h = 0; h < 2; h++) {
        const int c = 2 * pr + h;
        const unsigned char* bp = border + ((size_t)b * 16 + c) * (HH * WW);
        if (h) __syncthreads();        // everyone done reading tile before overwrite

        // ---- stage u8 -> f16: rows [ty0-11, ty0+139), cols [tx0-12, tx0+44) ----
        for (int i = threadIdx.x; i < R2 * 14; i += 256) {
            int iy = i / 14, cc = i - iy * 14;
            int gy  = ty0 - PAD2 + iy;
            int gx0 = tx0 - 12 + 4 * cc;        // 4-aligned
            unsigned u = 0;
            if (((unsigned)gy < HH) & ((unsigned)gx0 < WW))
                u = *(const unsigned*)(bp + (size_t)gy * WW + gx0);
            __half2 lo2 = __floats2half2_rn((float)(u & 255u), (float)((u >> 8) & 255u));
            __half2 hi2 = __floats2half2_rn((float)((u >> 16) & 255u), (float)(u >> 24));
            unsigned* dst = &tile[iy * F16ROW + 2 * cc];
            dst[0] = *(unsigned*)&lo2;
            dst[1] = *(unsigned*)&hi2;
        }
        __syncthreads();

        float acc[2][8];
        #pragma unroll
        for (int dy = 0; dy < 2; dy++)
            #pragma unroll
            for (int p = 0; p < 8; p++) acc[dy][p] = 0.f;

        const float* wc = Wg + c * (K2 * K2);

        // 7 full ky-blocks of 3 taps + tail of 2 (ky 21,22)
        #pragma unroll 1
        for (int kyb = 0; kyb < 7; kyb++) {
            const int b0 = kyb * 3;
            #pragma unroll
            for (int r = 0; r < 4; r++) {
                const int trow = py + b0 + r;
                unsigned d[16];                 // 32 f16: elements px .. px+31
                const uint4* tp4 = (const uint4*)&tile[trow * F16ROW + 4 * lx];
                #pragma unroll
                for (int rr = 0; rr < 4; rr++) *(uint4*)&d[4 * rr] = tp4[rr];
                #pragma unroll
                for (int jk = 0; jk < 3; jk++) {
                    const int dy = r - jk;
                    if (dy >= 0 && dy < 2) {
                        #pragma unroll
                        for (int kx = 0; kx < 23; kx++) {
                            const float wv = wc[(b0 + jk) * 23 + kx];
                            #pragma unroll
                            for (int p = 0; p < 8; p++) {
                                const int e = p + kx + 1;     // 1..30
                                __half2 h2 = *(__half2*)&d[e >> 1];
                                float xv = (e & 1) ? __high2float(h2) : __low2float(h2);
                                acc[dy][p] = fmaf(xv, wv, acc[dy][p]);  // -> v_fma_mix_f32
                            }
                        }
                    }
                }
            }
        }
        {   // tail: ky 21,22
            const int b0 = 21;
            #pragma unroll
            for (int r = 0; r < 3; r++) {
                const int trow = py + b0 + r;
                unsigned d[16];
                const uint4* tp4 = (const uint4*)&tile[trow * F16ROW + 4 * lx];
                #pragma unroll
                for (int rr = 0; rr < 4; rr++) *(uint4*)&d[4 * rr] = tp4[rr];
                #pragma unroll
                for (int jk = 0; jk < 2; jk++) {
                    const int dy = r - jk;
                    if (dy >= 0 && dy < 2) {
                        #pragma unroll
                        for (int kx = 0; kx < 23; kx++) {
                            const float wv = wc[(b0 + jk) * 23 + kx];
                            #pragma unroll
                            for (int p = 0; p < 8; p++) {
                                const int e = p + kx + 1;
                                __half2 h2 = *(__half2*)&d[e >> 1];
                                float xv = (e & 1) ? __high2float(h2) : __low2float(h2);
                                acc[dy][p] = fmaf(xv, wv, acc[dy][p]);
                            }
                        }
                    }
                }
            }
        }

        unsigned s = 0;
        #pragma unroll
        for (int dy = 0; dy < 2; dy++)
            #pragma unroll
            for (int p = 0; p < 8; p++)
                s |= (acc[dy][p] >= 1.f ? 1u : 0u) << (8 * dy + p);
        if (h == 0) sprev = s;
        else        term  = sprev & ~s;        // spike(conv_even) * (1 - spike(conv_odd))
    }

    // ---- write term plane (u8 {0,1}) ----
    const int ox = tx0 + px;
    unsigned char* gp = termp + ((size_t)b * 8 + pr) * (HH * WW);
    #pragma unroll
    for (int dy = 0; dy < 2; dy++) {
        unsigned lo = 0, hi = 0;
        #pragma unroll
        for (int p = 0; p < 4; p++) {
            lo |= ((term >> (8 * dy + p))     & 1u) << (8 * p);
            hi |= ((term >> (8 * dy + 4 + p)) & 1u) << (8 * p);
        }
        uint2 v; v.x = lo; v.y = hi;
        *(uint2*)&gp[(size_t)(ty0 + py + dy) * WW + ox] = v;
    }
}

// ---------------- Stage 3: sum 8 term planes -> output ----------------
__global__ __launch_bounds__(256) void combine_kernel(
    const unsigned char* __restrict__ termp, float* __restrict__ out)
{
    const int idx = blockIdx.x * 256 + threadIdx.x;   // uint granules
    const int b = idx >> 16;
    const int r = idx & 65535;
    const unsigned* g = (const unsigned*)termp;
    unsigned s = 0;
    #pragma unroll
    for (int p = 0; p < 8; p++)
        s += g[(size_t)(b * 8 + p) * 65536 + r];      // bytes <=1 each, sum <=8: no carry
    float4 f;
    f.x = (float)(s & 255u);
    f.y = (float)((s >> 8) & 255u);
    f.z = (float)((s >> 16) & 255u);
    f.w = (float)(s >> 24);
    ((float4*)out)[idx] = f;
}

extern "C" void kernel_launch(void* const* d_in, const int* in_sizes, int n_in,
                              void* d_out, int out_size, void* d_ws, size_t ws_size,
                              hipStream_t stream)
{
    const float* inp = (const float*)d_in[0];   // (4,2,512,512) f32
    const float* Wb  = (const float*)d_in[1];   // (8,1,11,11)   f32
    const float* Wg  = (const float*)d_in[2];   // (16,1,23,23)  f32
    unsigned char* border = (unsigned char*)d_ws;                       // 16.78 MB
    unsigned char* termp  = border + (size_t)NB * 16 * HH * WW;         // +8.39 MB
    float* out = (float*)d_out;                 // (4,512,512)   f32

    dim3 blk(256);
    dim3 g1(WW / T1X, HH / T1Y, NB);        // 16x32x4 = 2048 blocks
    stage1_kernel<<<g1, blk, 0, stream>>>(inp, Wb, border);
    dim3 g2(WW / T2X, HH / T2Y, NB * 8);    // 16x4x32 = 2048 blocks (pair per block)
    stage2_kernel<<<g2, blk, 0, stream>>>(border, Wg, termp);
    dim3 g3((NB * HH * WW / 4) / 256);      // 1024 blocks
    combine_kernel<<<g3, blk, 0, stream>>>(termp, out);
}

// Round 13
// 288.452 us; speedup vs baseline: 1.0942x; 1.0942x over previous
//
#include <hip/hip_runtime.h>

#define HH 512
#define WW 512
#define NB 4

// ---------------- Stage 1: 11x11 convs (1->8, pos & neg) + spike/WTA logic ----------------
// Round-11 version (2 px/thread, 2048 blocks). Stage1 proven insensitive to DS/s_load/TLP.
#define K1 11
#define PAD1 5
#define T1X 32
#define T1Y 16
#define IN1X 42
#define IN1Y 26
#define S1 44

__device__ __forceinline__ unsigned conv8_pass2(const float* __restrict__ sm,
                                                const float* __restrict__ Wb,
                                                int py, int px)
{
    float acc[8][2];
    #pragma unroll
    for (int c = 0; c < 8; c++) { acc[c][0] = 0.f; acc[c][1] = 0.f; }

    #pragma unroll 1
    for (int ky = 0; ky < K1; ky++) {
        const float2* rp = (const float2*)&sm[(py + ky) * S1 + px];
        float a[12];
        #pragma unroll
        for (int r = 0; r < 6; r++) *(float2*)&a[2 * r] = rp[r];
        #pragma unroll
        for (int c = 0; c < 8; c++) {
            #pragma unroll
            for (int kx = 0; kx < K1; kx++) {
                const float wv = Wb[c * 121 + ky * 11 + kx];
                acc[c][0] = fmaf(a[kx],     wv, acc[c][0]);
                acc[c][1] = fmaf(a[kx + 1], wv, acc[c][1]);
            }
        }
    }
    unsigned bits = 0;
    #pragma unroll
    for (int c = 0; c < 8; c++) {
        bits |= (acc[c][0] >= 1.f ? 1u : 0u) << (c * 2);
        bits |= (acc[c][1] >= 1.f ? 1u : 0u) << (c * 2 + 1);
    }
    return bits;
}

__global__ __launch_bounds__(256, 8) void stage1_kernel(
    const float* __restrict__ inp, const float* __restrict__ Wb,
    unsigned char* __restrict__ border)
{
    __shared__ __align__(16) float s0[IN1Y * S1];
    __shared__ __align__(16) float s1[IN1Y * S1];

    const int b   = blockIdx.z;
    const int tx0 = blockIdx.x * T1X;
    const int ty0 = blockIdx.y * T1Y;
    const float* in0 = inp + ((size_t)b * 2 + 0) * (HH * WW);
    const float* in1 = inp + ((size_t)b * 2 + 1) * (HH * WW);

    for (int i = threadIdx.x; i < IN1Y * IN1X; i += 256) {
        int iy = i / IN1X, ix = i - iy * IN1X;
        int gy = ty0 + iy - PAD1, gx = tx0 + ix - PAD1;
        bool ok = (gy >= 0) & (gy < HH) & (gx >= 0) & (gx < WW);
        int idx = gy * WW + gx;
        s0[iy * S1 + ix] = ok ? in0[idx] : 0.f;
        s1[iy * S1 + ix] = ok ? in1[idx] : 0.f;
    }
    __syncthreads();

    const int lx = threadIdx.x & 15;
    const int ly = threadIdx.x >> 4;
    const int px = lx * 2;
    const int py = ly;

    const unsigned bitP = conv8_pass2(s0, Wb, py, px);
    const unsigned bitN = conv8_pass2(s1, Wb, py, px);

    const int gy = ty0 + py;
    const int gxbase = tx0 + px;

    float vm[2];
    #pragma unroll
    for (int p = 0; p < 2; p++)
        vm[p] = s0[(py + PAD1) * S1 + px + PAD1 + p]
              + s1[(py + PAD1) * S1 + px + PAD1 + p];

    float b13[4][2], b24[4][2];
    #pragma unroll
    for (int o = 0; o < 4; o++) {
        #pragma unroll
        for (int p = 0; p < 2; p++) {
            float pe = (float)((bitP >> (4 * o + p))     & 1u);
            float po = (float)((bitP >> (4 * o + 2 + p)) & 1u);
            float ne = (float)((bitN >> (4 * o + p))     & 1u);
            float no = (float)((bitN >> (4 * o + 2 + p)) & 1u);
            float sa = (vm[p] * (pe - 1.5f * no) >= 1.f) ? 1.f : 0.f;
            float sb = (vm[p] * (ne - 1.5f * po) >= 1.f) ? 1.f : 0.f;
            b13[o][p] = sa + sb;
            float sc = (vm[p] * (po - 1.5f * ne) >= 1.f) ? 1.f : 0.f;
            float sd = (vm[p] * (no - 1.5f * pe) >= 1.f) ? 1.f : 0.f;
            b24[o][p] = sc + sd;
        }
    }
    float mxp[2];
    #pragma unroll
    for (int p = 0; p < 2; p++) {
        float m = 0.f;
        #pragma unroll
        for (int o = 0; o < 4; o++) m = fmaxf(m, fabsf(b13[o][p] - b24[o][p]));
        mxp[p] = m;
    }
    #pragma unroll
    for (int o = 0; o < 4; o++) {
        unsigned short w0 = 0, w1 = 0, w2 = 0, w3 = 0;
        #pragma unroll
        for (int p = 0; p < 2; p++) {
            float d   = b13[o][p] - b24[o][p];
            float wta = (fabsf(d) == mxp[p]) ? 1.f : 0.f;
            float b1p = (wta * d >= 1.f)    ? 1.f : 0.f;
            float b1n = (-(wta * d) >= 1.f) ? 1.f : 0.f;
            w0 |= (unsigned short)(unsigned char)(b1p * b13[o][p]) << (8 * p);
            w1 |= (unsigned short)(unsigned char)(b1p * b24[o][p]) << (8 * p);
            w2 |= (unsigned short)(unsigned char)(b1n * b24[o][p]) << (8 * p);
            w3 |= (unsigned short)(unsigned char)(b1n * b13[o][p]) << (8 * p);
        }
        size_t base = (((size_t)b * 16 + 4 * o) * HH + gy) * WW + gxbase;
        *(unsigned short*)&border[base]                       = w0;
        *(unsigned short*)&border[base + (size_t)HH * WW]     = w1;
        *(unsigned short*)&border[base + (size_t)2 * HH * WW] = w2;
        *(unsigned short*)&border[base + (size_t)3 * HH * WW] = w3;
    }
}

// ---------------- Stage 2: depthwise 23x23 conv, u8 LDS tile + ky-blocking ----------------
// EXACT round-9 version (185 us, VGPR=64, no spill, conflicts 1.04e7).
#define K2 23
#define PAD2 11
#define T2X 32
#define T2Y 128
#define SROW 18        // LDS row stride in dwords (72 B)
#define R2 150         // staged rows: ty0-11 .. ty0+138

__device__ __forceinline__ float ubyte_f(unsigned dw, int byi) {
    return (float)((dw >> (8 * byi)) & 0xffu);   // -> v_cvt_f32_ubyteN
}

__global__ __launch_bounds__(256, 4) void stage2_kernel(
    const unsigned char* __restrict__ border, const float* __restrict__ Wg,
    unsigned char* __restrict__ gsp)
{
    __shared__ unsigned tile[R2 * SROW];   // u8 tile, 10.8 KB

    const int z   = blockIdx.z;
    const int b   = z >> 4;
    const int c   = z & 15;
    const int tx0 = blockIdx.x * T2X;
    const int ty0 = blockIdx.y * T2Y;
    const unsigned char* bp = border + ((size_t)b * 16 + c) * (HH * WW);

    // ---- stage u8 rows [ty0-11, ty0+139), cols [tx0-12, tx0+52) as dwords ----
    for (int i = threadIdx.x; i < R2 * 16; i += 256) {
        int iy = i >> 4, cc = i & 15;
        int gy  = ty0 - PAD2 + iy;
        int gx0 = tx0 - 12 + 4 * cc;       // 4-aligned; in range iff 0<=gx0<=508
        unsigned u = 0;
        if (((unsigned)gy < HH) & ((unsigned)gx0 < WW))
            u = *(const unsigned*)(bp + (size_t)gy * WW + gx0);
        tile[iy * SROW + cc] = u;
    }
    __syncthreads();

    const int lx = threadIdx.x & 3;    // 4 x-groups of 8 px -> 32 wide
    const int ly = threadIdx.x >> 2;   // 64 y-groups of 2 rows -> 128 tall
    const int px = lx * 8;
    const int py = ly * 2;

    float acc[2][8];
    #pragma unroll
    for (int dy = 0; dy < 2; dy++)
        #pragma unroll
        for (int p = 0; p < 8; p++) acc[dy][p] = 0.f;

    const float* wc = Wg + c * (K2 * K2);

    // 7 full ky-blocks of 3 taps, then a tail block of 2 (ky 21,22)
    #pragma unroll 1
    for (int kyb = 0; kyb < 7; kyb++) {
        const int b0 = kyb * 3;
        #pragma unroll
        for (int r = 0; r < 4; r++) {                  // input rows py+b0+r
            const int trow = py + b0 + r;
            unsigned d[8];
            const uint2* tp2 = (const uint2*)&tile[trow * SROW + 2 * lx];
            #pragma unroll
            for (int r2 = 0; r2 < 4; r2++) { uint2 v = tp2[r2]; d[2*r2] = v.x; d[2*r2+1] = v.y; }
            float a[31];
            #pragma unroll
            for (int j = 1; j <= 30; j++) a[j] = ubyte_f(d[j >> 2], j & 3);
            #pragma unroll
            for (int jk = 0; jk < 3; jk++) {
                const int dy = r - jk;
                if (dy >= 0 && dy < 2) {               // compile-time after unroll
                    #pragma unroll
                    for (int kx = 0; kx < 23; kx++) {
                        const float wv = wc[(b0 + jk) * 23 + kx];   // uniform -> s_load
                        #pragma unroll
                        for (int p = 0; p < 8; p++)
                            acc[dy][p] = fmaf(a[p + kx + 1], wv, acc[dy][p]);
                    }
                }
            }
        }
    }
    {   // tail: ky 21,22
        const int b0 = 21;
        #pragma unroll
        for (int r = 0; r < 3; r++) {
            const int trow = py + b0 + r;
            unsigned d[8];
            const uint2* tp2 = (const uint2*)&tile[trow * SROW + 2 * lx];
            #pragma unroll
            for (int r2 = 0; r2 < 4; r2++) { uint2 v = tp2[r2]; d[2*r2] = v.x; d[2*r2+1] = v.y; }
            float a[31];
            #pragma unroll
            for (int j = 1; j <= 30; j++) a[j] = ubyte_f(d[j >> 2], j & 3);
            #pragma unroll
            for (int jk = 0; jk < 2; jk++) {
                const int dy = r - jk;
                if (dy >= 0 && dy < 2) {
                    #pragma unroll
                    for (int kx = 0; kx < 23; kx++) {
                        const float wv = wc[(b0 + jk) * 23 + kx];
                        #pragma unroll
                        for (int p = 0; p < 8; p++)
                            acc[dy][p] = fmaf(a[p + kx + 1], wv, acc[dy][p]);
                    }
                }
            }
        }
    }

    // ---- spike + write u8 plane ----
    const int ox = tx0 + px;               // multiple of 8 -> uint2 store OK
    unsigned char* gp = gsp + ((size_t)b * 16 + c) * (HH * WW);
    #pragma unroll
    for (int dy = 0; dy < 2; dy++) {
        const int oy = ty0 + py + dy;
        unsigned lo = 0, hi = 0;
        #pragma unroll
        for (int p = 0; p < 4; p++) lo |= (acc[dy][p]     >= 1.f ? 1u : 0u) << (8 * p);
        #pragma unroll
        for (int p = 0; p < 4; p++) hi |= (acc[dy][p + 4] >= 1.f ? 1u : 0u) << (8 * p);
        uint2 v; v.x = lo; v.y = hi;
        *(uint2*)&gp[(size_t)oy * WW + ox] = v;
    }
}

// ---------------- Stage 3: combine 16 spike planes -> output ----------------
__global__ __launch_bounds__(256) void combine_kernel(
    const unsigned char* __restrict__ gsp, float* __restrict__ out)
{
    const int idx = blockIdx.x * 256 + threadIdx.x;   // uint granules
    const int b = idx >> 16;
    const int r = idx & 65535;
    const unsigned* g = (const unsigned*)gsp;
    const int pb = b * 16;
    unsigned s = 0;
    #pragma unroll
    for (int o = 0; o < 4; o++) {
        unsigned g0 = g[(size_t)(pb + 4 * o + 0) * 65536 + r];
        unsigned g1 = g[(size_t)(pb + 4 * o + 1) * 65536 + r];
        unsigned g2 = g[(size_t)(pb + 4 * o + 2) * 65536 + r];
        unsigned g3 = g[(size_t)(pb + 4 * o + 3) * 65536 + r];
        s += ((g0 & ~g1) & 0x01010101u) + ((g2 & ~g3) & 0x01010101u);
    }
    float4 f;
    f.x = (float)(s & 255u);
    f.y = (float)((s >> 8) & 255u);
    f.z = (float)((s >> 16) & 255u);
    f.w = (float)(s >> 24);
    ((float4*)out)[idx] = f;
}

extern "C" void kernel_launch(void* const* d_in, const int* in_sizes, int n_in,
                              void* d_out, int out_size, void* d_ws, size_t ws_size,
                              hipStream_t stream)
{
    const float* inp = (const float*)d_in[0];   // (4,2,512,512) f32
    const float* Wb  = (const float*)d_in[1];   // (8,1,11,11)   f32
    const float* Wg  = (const float*)d_in[2];   // (16,1,23,23)  f32
    unsigned char* border = (unsigned char*)d_ws;                       // 16.78 MB
    unsigned char* gsp    = border + (size_t)NB * 16 * HH * WW;         // +16.78 MB
    float* out = (float*)d_out;                 // (4,512,512)   f32

    dim3 blk(256);
    dim3 g1(WW / T1X, HH / T1Y, NB);        // 16x32x4 = 2048 blocks
    stage1_kernel<<<g1, blk, 0, stream>>>(inp, Wb, border);
    dim3 g2(WW / T2X, HH / T2Y, NB * 16);   // 16x4x64 = 4096 blocks
    stage2_kernel<<<g2, blk, 0, stream>>>(border, Wg, gsp);
    dim3 g3((NB * HH * WW / 4) / 256);      // 1024 blocks
    combine_kernel<<<g3, blk, 0, stream>>>(gsp, out);
}